// Round 8
// baseline (707.711 us; speedup 1.0000x reference)
//
#include <hip/hip_runtime.h>
#include <hip/hip_bf16.h>

typedef unsigned short u16;
typedef unsigned int u32;
typedef short bf16x8 __attribute__((ext_vector_type(8)));
typedef float f32x4 __attribute__((ext_vector_type(4)));

#define MFMA_BF16 __builtin_amdgcn_mfma_f32_16x16x32_bf16

#define B_   2
#define S_   2048
#define E_   2048
#define H_   16
#define KVH_ 4
#define D_   128
#define M_   (B_ * S_)      // 4096 rows (b,s)
#define NQKV 3072           // 2048 q + 512 k + 512 v
#define SCALE_ 0.08838834764831845f  // 1/sqrt(128)

__device__ __forceinline__ float b2f(u16 u) {
    union { u32 i; float f; } x; x.i = ((u32)u) << 16; return x.f;
}
__device__ __forceinline__ u16 f2b(float f) {
    __hip_bfloat16 h = __float2bfloat16(f);
    return *reinterpret_cast<u16*>(&h);
}

// Runtime dtype probe (R5 diag: all inputs are f32 in memory; kept for safety).
__device__ __forceinline__ bool is_f32_mat(const void* p) {
    const u16* q = (const u16*)p;
    int good = 0;
    #pragma unroll
    for (int i = 0; i < 32; ++i) {
        int e = (q[i] >> 7) & 0xFF;
        good += (e >= 90 && e <= 140) ? 1 : 0;
    }
    return good < 28;
}

// Load 8 logical elements (element offset eoff) as 8 bf16 packed in a uint4.
__device__ __forceinline__ uint4 ld8(const void* base, size_t eoff, bool f32mode) {
    if (!f32mode)
        return *reinterpret_cast<const uint4*>((const u16*)base + eoff);
    const float* p = (const float*)base + eoff;
    float4 a = *reinterpret_cast<const float4*>(p);
    float4 b = *reinterpret_cast<const float4*>(p + 4);
    union { uint4 v; u16 h[8]; } pk;
    pk.h[0] = f2b(a.x); pk.h[1] = f2b(a.y); pk.h[2] = f2b(a.z); pk.h[3] = f2b(a.w);
    pk.h[4] = f2b(b.x); pk.h[5] = f2b(b.y); pk.h[6] = f2b(b.z); pk.h[7] = f2b(b.w);
    return pk.v;
}

// ---------------------------------------------------------------------------
// Kernel 1: QKV projection gemm_bt.  C[m,n] = sum_k x[m,k]*w[n,k] -> qkvraw.
// ---------------------------------------------------------------------------
__global__ __launch_bounds__(256)
void qkv_gemm_kernel(const void* __restrict__ x, const void* __restrict__ wq,
                     const void* __restrict__ wk, const void* __restrict__ wv,
                     u16* __restrict__ qkvraw) {
    __shared__ __align__(16) u16 As[128][72];
    __shared__ __align__(16) u16 Bs[128][72];
    const int tid  = threadIdx.x;
    const int wave = tid >> 6, lane = tid & 63, l15 = lane & 15, quad = lane >> 4;
    const int wm = wave & 1, wn = wave >> 1;
    const int m0 = blockIdx.y * 128, n0 = blockIdx.x * 128;

    const void* wptr; int nb;
    if (n0 < 2048)      { wptr = wq; nb = n0; }
    else if (n0 < 2560) { wptr = wk; nb = n0 - 2048; }
    else                { wptr = wv; nb = n0 - 2560; }

    const bool xf32 = is_f32_mat(x);
    const bool wf32 = is_f32_mat(wptr);

    f32x4 acc[4][4];
    const f32x4 zero4 = {0.f, 0.f, 0.f, 0.f};
    for (int i = 0; i < 4; ++i)
        for (int j = 0; j < 4; ++j) acc[i][j] = zero4;

    for (int kt = 0; kt < E_; kt += 64) {
        __syncthreads();
        #pragma unroll
        for (int i = 0; i < 4; ++i) {
            int c = tid + i * 256;
            int row = c >> 3, kc = (c & 7) * 8;
            *reinterpret_cast<uint4*>(&As[row][kc]) =
                ld8(x, (size_t)(m0 + row) * E_ + kt + kc, xf32);
            *reinterpret_cast<uint4*>(&Bs[row][kc]) =
                ld8(wptr, (size_t)(nb + row) * E_ + kt + kc, wf32);
        }
        __syncthreads();
        #pragma unroll
        for (int kk = 0; kk < 64; kk += 32) {
            bf16x8 af[4], bfr[4];
            #pragma unroll
            for (int i = 0; i < 4; ++i) {
                af[i]  = *reinterpret_cast<const bf16x8*>(&As[wm * 64 + i * 16 + l15][kk + quad * 8]);
                bfr[i] = *reinterpret_cast<const bf16x8*>(&Bs[wn * 64 + i * 16 + l15][kk + quad * 8]);
            }
            #pragma unroll
            for (int mi = 0; mi < 4; ++mi)
                #pragma unroll
                for (int ni = 0; ni < 4; ++ni)
                    acc[mi][ni] = MFMA_BF16(af[mi], bfr[ni], acc[mi][ni], 0, 0, 0);
        }
    }

    const int mb = m0 + wm * 64, nbase = n0 + wn * 64;
    #pragma unroll
    for (int mi = 0; mi < 4; ++mi)
        #pragma unroll
        for (int ni = 0; ni < 4; ++ni)
            #pragma unroll
            for (int r = 0; r < 4; ++r) {
                int m = mb + mi * 16 + quad * 4 + r;   // C/D: row = quad*4+reg
                int n = nbase + ni * 16 + l15;         //      col = lane&15
                qkvraw[(size_t)m * NQKV + n] = f2b(acc[mi][ni][r]);
            }
}

// ---------------------------------------------------------------------------
// Kernel 1.5: elementwise RoPE + scatter.  One thread per (even,odd) pair.
// ---------------------------------------------------------------------------
__global__ __launch_bounds__(256)
void rope_scatter_kernel(const u16* __restrict__ qkvraw,
                         const void* __restrict__ fc, const void* __restrict__ fs,
                         u16* __restrict__ Qr, u16* __restrict__ Kr,
                         u16* __restrict__ Vr) {
    const int pc = blockIdx.x * 256 + threadIdx.x;   // pair column [0,1536)
    const int m  = blockIdx.y;                       // row [0,4096)
    const int n  = pc * 2;
    const int b  = m >> 11, s = m & 2047;

    u32 raw = *reinterpret_cast<const u32*>(qkvraw + (size_t)m * NQKV + n);
    float xr = b2f((u16)(raw & 0xFFFF));
    float xi = b2f((u16)(raw >> 16));

    if (n < 2560) {                                  // RoPE for q and k
        const bool ff32 = (((const u16*)fc)[0] != 0x3F80);  // cos(0)=1.0 probe
        int d  = n & 127;
        int fi = s * 64 + (d >> 1);
        float c  = ff32 ? ((const float*)fc)[fi] : b2f(((const u16*)fc)[fi]);
        float sn = ff32 ? ((const float*)fs)[fi] : b2f(((const u16*)fs)[fi]);
        float orr = xr * c - xi * sn;
        float oi  = xr * sn + xi * c;
        xr = orr; xi = oi;
    }
    u32 pk = (u32)f2b(xr) | ((u32)f2b(xi) << 16);

    if (n < 2048) {
        int h = n >> 7, d = n & 127;
        *reinterpret_cast<u32*>(&Qr[((size_t)(b * H_ + h) * S_ + s) * D_ + d]) = pk;
    } else if (n < 2560) {
        int kh = (n - 2048) >> 7, d = n & 127;
        *reinterpret_cast<u32*>(&Kr[((size_t)(b * KVH_ + kh) * S_ + s) * D_ + d]) = pk;
    } else {
        int kh = (n - 2560) >> 7, d = n & 127;
        *reinterpret_cast<u32*>(&Vr[((size_t)(b * KVH_ + kh) * S_ + s) * D_ + d]) = pk;
    }
}

// ---------------------------------------------------------------------------
// Kernel 2: causal flash attention.  GQA per shown jnp.tile: kvh = h % KVH.
// ---------------------------------------------------------------------------
__device__ __forceinline__ int vswz(int d, int k) {   // XOR swizzle on k bits 3..4
    return k ^ (((d >> 3) & 3) << 3);
}

__global__ __launch_bounds__(256)
void flash_kernel(const u16* __restrict__ Qr, const u16* __restrict__ Kr,
                  const u16* __restrict__ Vr, u16* __restrict__ AO) {
    __shared__ __align__(16) u16 Ks[32][136];     // [kv][d], pad 8
    __shared__ __align__(16) u16 Vt[128][40];     // [d][kv] transposed, swizzled
    __shared__ __align__(16) u16 Ps[4][32][40];   // per-wave P round-trip
    const int tid  = threadIdx.x;
    const int wave = tid >> 6, lane = tid & 63, l15 = lane & 15, quad = lane >> 4;
    const int qt = blockIdx.x, h = blockIdx.y, b = blockIdx.z;
    const int kvh = h & 3;                        // jnp.tile => modulo mapping
    const u16* Qb = Qr + (size_t)(b * H_ + h) * S_ * D_;
    const u16* Kb = Kr + (size_t)(b * KVH_ + kvh) * S_ * D_;
    const u16* Vb = Vr + (size_t)(b * KVH_ + kvh) * S_ * D_;
    const int q0 = qt * 128 + wave * 32;

    bf16x8 aq[2][4];   // A-op: m=lane&15, k=quad*8+j
    #pragma unroll
    for (int mi = 0; mi < 2; ++mi)
        #pragma unroll
        for (int kk = 0; kk < 4; ++kk)
            aq[mi][kk] = *reinterpret_cast<const bf16x8*>(
                Qb + (size_t)(q0 + mi * 16 + l15) * D_ + kk * 32 + quad * 8);

    f32x4 o[2][8];
    const f32x4 zero4 = {0.f, 0.f, 0.f, 0.f};
    for (int i = 0; i < 2; ++i)
        for (int j = 0; j < 8; ++j) o[i][j] = zero4;
    float mst[2][4], lst[2][4];
    for (int i = 0; i < 2; ++i)
        for (int r = 0; r < 4; ++r) { mst[i][r] = -__builtin_inff(); lst[i][r] = 0.f; }

    const int ntiles = (qt + 1) * 4;
    for (int j = 0; j < ntiles; ++j) {
        const int kv0 = j * 32;
        __syncthreads();
        #pragma unroll
        for (int i = 0; i < 2; ++i) {
            int c = tid + i * 256;
            int r = c >> 4, c8 = (c & 15) * 8;
            *reinterpret_cast<uint4*>(&Ks[r][c8]) =
                *reinterpret_cast<const uint4*>(Kb + (size_t)(kv0 + r) * D_ + c8);
            bf16x8 tv = *reinterpret_cast<const bf16x8*>(Vb + (size_t)(kv0 + r) * D_ + c8);
            const u16* tp = reinterpret_cast<const u16*>(&tv);
            #pragma unroll
            for (int e = 0; e < 8; ++e) Vt[c8 + e][vswz(c8 + e, r)] = tp[e];
        }
        __syncthreads();

        f32x4 sc[2][2];
        for (int mi = 0; mi < 2; ++mi)
            for (int ni = 0; ni < 2; ++ni) sc[mi][ni] = zero4;
        #pragma unroll
        for (int kk = 0; kk < 4; ++kk) {
            bf16x8 bk0 = *reinterpret_cast<const bf16x8*>(&Ks[l15][kk * 32 + quad * 8]);
            bf16x8 bk1 = *reinterpret_cast<const bf16x8*>(&Ks[16 + l15][kk * 32 + quad * 8]);
            #pragma unroll
            for (int mi = 0; mi < 2; ++mi) {
                sc[mi][0] = MFMA_BF16(aq[mi][kk], bk0, sc[mi][0], 0, 0, 0);
                sc[mi][1] = MFMA_BF16(aq[mi][kk], bk1, sc[mi][1], 0, 0, 0);
            }
        }

        float al[2][4];
        #pragma unroll
        for (int mi = 0; mi < 2; ++mi) {
            #pragma unroll
            for (int r = 0; r < 4; ++r) {
                int qg = q0 + mi * 16 + quad * 4 + r;
                float s0 = sc[mi][0][r] * SCALE_;
                float s1 = sc[mi][1][r] * SCALE_;
                if (kv0 + l15 > qg)      s0 = -__builtin_inff();
                if (kv0 + 16 + l15 > qg) s1 = -__builtin_inff();
                float mx = fmaxf(s0, s1);
                #pragma unroll
                for (int off = 1; off < 16; off <<= 1) mx = fmaxf(mx, __shfl_xor(mx, off));
                float mnew = fmaxf(mst[mi][r], mx);
                float a  = __expf(mst[mi][r] - mnew);
                float p0 = __expf(s0 - mnew);
                float p1 = __expf(s1 - mnew);
                float sum = p0 + p1;
                #pragma unroll
                for (int off = 1; off < 16; off <<= 1) sum += __shfl_xor(sum, off);
                lst[mi][r] = lst[mi][r] * a + sum;
                mst[mi][r] = mnew;
                al[mi][r] = a;
                int prow = mi * 16 + quad * 4 + r;
                Ps[wave][prow][l15]      = f2b(p0);
                Ps[wave][prow][16 + l15] = f2b(p1);
            }
        }
        #pragma unroll
        for (int mi = 0; mi < 2; ++mi)
            #pragma unroll
            for (int ni = 0; ni < 8; ++ni)
                #pragma unroll
                for (int r = 0; r < 4; ++r) o[mi][ni][r] *= al[mi][r];

        __syncthreads();

        bf16x8 ap[2];
        #pragma unroll
        for (int mi = 0; mi < 2; ++mi)
            ap[mi] = *reinterpret_cast<const bf16x8*>(&Ps[wave][mi * 16 + l15][quad * 8]);
        #pragma unroll
        for (int ni = 0; ni < 8; ++ni) {
            int n = ni * 16 + l15;
            bf16x8 bv = *reinterpret_cast<const bf16x8*>(&Vt[n][vswz(n, quad * 8)]);
            o[0][ni] = MFMA_BF16(ap[0], bv, o[0][ni], 0, 0, 0);
            o[1][ni] = MFMA_BF16(ap[1], bv, o[1][ni], 0, 0, 0);
        }
    }

    #pragma unroll
    for (int mi = 0; mi < 2; ++mi)
        #pragma unroll
        for (int r = 0; r < 4; ++r) {
            float inv = 1.0f / lst[mi][r];
            int qg = q0 + mi * 16 + quad * 4 + r;
            size_t base = ((size_t)(b * S_ + qg)) * E_ + h * D_;
            #pragma unroll
            for (int ni = 0; ni < 8; ++ni)
                AO[base + ni * 16 + l15] = f2b(o[mi][ni][r] * inv);
        }
}

// ---------------------------------------------------------------------------
// Kernel 3: output projection.  out[m,n] = sum_e AO[m,e]*wo[n,e].
// OUTPUT IS FLOAT32 (R7 probe: d_out readback is f32, not bf16).
// ---------------------------------------------------------------------------
__global__ __launch_bounds__(256)
void out_proj_kernel(const u16* __restrict__ ao, const void* __restrict__ wo,
                     float* __restrict__ out) {
    __shared__ __align__(16) u16 As[128][72];
    __shared__ __align__(16) u16 Bs[128][72];
    const int tid  = threadIdx.x;
    const int wave = tid >> 6, lane = tid & 63, l15 = lane & 15, quad = lane >> 4;
    const int wm = wave & 1, wn = wave >> 1;
    const int m0 = blockIdx.y * 128, n0 = blockIdx.x * 128;
    const bool wf32 = is_f32_mat(wo);

    f32x4 acc[4][4];
    const f32x4 zero4 = {0.f, 0.f, 0.f, 0.f};
    for (int i = 0; i < 4; ++i)
        for (int j = 0; j < 4; ++j) acc[i][j] = zero4;

    for (int kt = 0; kt < E_; kt += 64) {
        __syncthreads();
        #pragma unroll
        for (int i = 0; i < 4; ++i) {
            int c = tid + i * 256;
            int row = c >> 3, kc = (c & 7) * 8;
            *reinterpret_cast<uint4*>(&As[row][kc]) =
                *reinterpret_cast<const uint4*>(ao + (size_t)(m0 + row) * E_ + kt + kc);
            *reinterpret_cast<uint4*>(&Bs[row][kc]) =
                ld8(wo, (size_t)(n0 + row) * E_ + kt + kc, wf32);
        }
        __syncthreads();
        #pragma unroll
        for (int kk = 0; kk < 64; kk += 32) {
            bf16x8 af[4], bfr[4];
            #pragma unroll
            for (int i = 0; i < 4; ++i) {
                af[i]  = *reinterpret_cast<const bf16x8*>(&As[wm * 64 + i * 16 + l15][kk + quad * 8]);
                bfr[i] = *reinterpret_cast<const bf16x8*>(&Bs[wn * 64 + i * 16 + l15][kk + quad * 8]);
            }
            #pragma unroll
            for (int mi = 0; mi < 4; ++mi)
                #pragma unroll
                for (int ni = 0; ni < 4; ++ni)
                    acc[mi][ni] = MFMA_BF16(af[mi], bfr[ni], acc[mi][ni], 0, 0, 0);
        }
    }

    const int mb = m0 + wm * 64, nbase = n0 + wn * 64;
    #pragma unroll
    for (int mi = 0; mi < 4; ++mi)
        #pragma unroll
        for (int ni = 0; ni < 4; ++ni)
            #pragma unroll
            for (int r = 0; r < 4; ++r) {
                int m = mb + mi * 16 + quad * 4 + r;
                int n = nbase + ni * 16 + l15;
                out[(size_t)m * E_ + n] = acc[mi][ni][r];   // FLOAT32 store
            }
}

// ---------------------------------------------------------------------------
extern "C" void kernel_launch(void* const* d_in, const int* in_sizes, int n_in,
                              void* d_out, int out_size, void* d_ws, size_t ws_size,
                              hipStream_t stream) {
    const void* x  = d_in[0];
    const void* wq = d_in[1];
    const void* wk = d_in[2];
    const void* wv = d_in[3];
    const void* wo = d_in[4];
    const void* fc = d_in[5];
    const void* fs = d_in[6];
    float* out = (float*)d_out;        // f32 output (R7 probe evidence)

    // Workspace (48 MB): QKVraw 24 MB (reused as AO after rope_scatter -- WAR
    // is stream-ordered), Qr 16 MB, Kr 4 MB, Vr 4 MB.
    u16* QKVraw = (u16*)d_ws;
    u16* AO     = QKVraw;
    u16* Qr = QKVraw + (size_t)M_ * NQKV;
    u16* Kr = Qr + (size_t)B_ * H_ * S_ * D_;
    u16* Vr = Kr + (size_t)B_ * KVH_ * S_ * D_;

    qkv_gemm_kernel<<<dim3(NQKV / 128, M_ / 128), 256, 0, stream>>>(
        x, wq, wk, wv, QKVraw);
    rope_scatter_kernel<<<dim3(NQKV / 2 / 256, M_), 256, 0, stream>>>(
        QKVraw, fc, fs, Qr, Kr, Vr);
    flash_kernel<<<dim3(S_ / 128, H_, B_), 256, 0, stream>>>(Qr, Kr, Vr, AO);
    out_proj_kernel<<<dim3(E_ / 128, M_ / 128), 256, 0, stream>>>(AO, wo, out);
}

// Round 9
// 579.207 us; speedup vs baseline: 1.2219x; 1.2219x over previous
//
#include <hip/hip_runtime.h>
#include <hip/hip_bf16.h>

typedef unsigned short u16;
typedef unsigned int u32;
typedef short bf16x8 __attribute__((ext_vector_type(8)));
typedef float f32x4 __attribute__((ext_vector_type(4)));

#define MFMA_BF16 __builtin_amdgcn_mfma_f32_16x16x32_bf16

#define B_   2
#define S_   2048
#define E_   2048
#define H_   16
#define KVH_ 4
#define D_   128
#define M_   (B_ * S_)
#define NQKV 3072
#define SCALE_ 0.08838834764831845f  // 1/sqrt(128)

__device__ __forceinline__ float b2f(u16 u) {
    union { u32 i; float f; } x; x.i = ((u32)u) << 16; return x.f;
}
__device__ __forceinline__ u16 f2b(float f) {
    __hip_bfloat16 h = __float2bfloat16(f);
    return *reinterpret_cast<u16*>(&h);
}

// async 16B global->LDS: HW writes lds_base + lane*16  [m97 pattern]
__device__ __forceinline__ void async16(const u16* g, u16* l) {
    __builtin_amdgcn_global_load_lds(
        (const __attribute__((address_space(1))) void*)g,
        (__attribute__((address_space(3))) void*)l, 16, 0, 0);
}

__device__ __forceinline__ uint4 pack8(const float* p) {
    float4 a = *reinterpret_cast<const float4*>(p);
    float4 b = *reinterpret_cast<const float4*>(p + 4);
    union { uint4 v; u16 h[8]; } pk;
    pk.h[0] = f2b(a.x); pk.h[1] = f2b(a.y); pk.h[2] = f2b(a.z); pk.h[3] = f2b(a.w);
    pk.h[4] = f2b(b.x); pk.h[5] = f2b(b.y); pk.h[6] = f2b(b.z); pk.h[7] = f2b(b.w);
    return pk.v;
}

// ---------------------------------------------------------------------------
// f32 -> bf16 bulk convert, two regions per launch (region2 may be unused).
// 2048 elems per block.
// ---------------------------------------------------------------------------
__global__ __launch_bounds__(256)
void conv_kernel(const float* __restrict__ s1, u16* __restrict__ d1, int nblk1,
                 const float* __restrict__ s2, u16* __restrict__ d2) {
    int bid = blockIdx.x;
    const float* s; u16* d; size_t base;
    if (bid < nblk1) { s = s1; d = d1; base = (size_t)bid * 2048; }
    else             { s = s2; d = d2; base = (size_t)(bid - nblk1) * 2048; }
    size_t i = base + (size_t)threadIdx.x * 8;
    *reinterpret_cast<uint4*>(d + i) = pack8(s + i);
}

// ---------------------------------------------------------------------------
// Kernel 1: fused QKV gemm_bt + RoPE epilogue.
// 128x128 tile, BK=64. Fragment-major LDS (16 blocks of 1024B per tile):
// block t=(mb<<1|kb) holds lane l's A[mb*16+(l&15)][kb*32+(l>>4)*8 ..+7] at
// t*1024 + l*16 -> staging (async16) and ds_read_b128 use identical lane
// mapping => conflict-free LDS, no VALU cvt for x/wq (pre-converted bf16).
// wk/wv n-tiles (1/3 of grid) stage B from f32 with in-kernel cvt.
// Epilogue: RoPE via shfl_xor(1) pair partner, scatter to Qr/Kr/Vr.
// ---------------------------------------------------------------------------
__global__ __launch_bounds__(256)
void qkv_rope_gemm(const u16* __restrict__ xb, const u16* __restrict__ wqb,
                   const float* __restrict__ wk, const float* __restrict__ wv,
                   const float* __restrict__ fc, const float* __restrict__ fs,
                   u16* __restrict__ Qr, u16* __restrict__ Kr,
                   u16* __restrict__ Vr) {
    __shared__ __align__(16) u16 As[8192];   // 16 KB
    __shared__ __align__(16) u16 Bs[8192];   // 16 KB
    const int tid = threadIdx.x, wave = tid >> 6, lane = tid & 63;
    const int l15 = lane & 15, quad = lane >> 4;
    const int wm = wave & 1, wn = wave >> 1;
    const int m0 = blockIdx.y * 128, n0 = blockIdx.x * 128;

    const bool qpart = (n0 < 2048);
    const float* wf32 = nullptr; int nb = 0;
    if (n0 >= 2560)      { wf32 = wv; nb = n0 - 2560; }
    else if (n0 >= 2048) { wf32 = wk; nb = n0 - 2048; }

    f32x4 acc[4][4];
    const f32x4 zero4 = {0.f, 0.f, 0.f, 0.f};
    for (int i = 0; i < 4; ++i)
        for (int j = 0; j < 4; ++j) acc[i][j] = zero4;

    for (int kt = 0; kt < E_; kt += 64) {
        __syncthreads();
        #pragma unroll
        for (int j = 0; j < 4; ++j) {               // A tile: async per wave
            int t = wave * 4 + j;
            int row = m0 + (t >> 1) * 16 + l15;
            int col = kt + (t & 1) * 32 + quad * 8;
            async16(xb + (size_t)row * E_ + col, &As[t * 512]);
        }
        if (qpart) {
            #pragma unroll
            for (int j = 0; j < 4; ++j) {           // B tile: async (bf16 wq)
                int t = wave * 4 + j;
                int row = n0 + (t >> 1) * 16 + l15;
                int col = kt + (t & 1) * 32 + quad * 8;
                async16(wqb + (size_t)row * E_ + col, &Bs[t * 512]);
            }
        } else {
            #pragma unroll
            for (int p = 0; p < 4; ++p) {           // B tile: f32 cvt (wk/wv)
                int t = p * 4 + wave;
                int row = nb + (t >> 1) * 16 + l15;
                int col = kt + (t & 1) * 32 + quad * 8;
                *reinterpret_cast<uint4*>(&Bs[t * 512 + lane * 8]) =
                    pack8(wf32 + (size_t)row * E_ + col);
            }
        }
        __syncthreads();
        #pragma unroll
        for (int kb = 0; kb < 2; ++kb) {
            bf16x8 af[4], bfr[4];
            #pragma unroll
            for (int i = 0; i < 4; ++i) {
                af[i]  = *reinterpret_cast<const bf16x8*>(
                    &As[(((wm * 4 + i) << 1) | kb) * 512 + lane * 8]);
                bfr[i] = *reinterpret_cast<const bf16x8*>(
                    &Bs[(((wn * 4 + i) << 1) | kb) * 512 + lane * 8]);
            }
            #pragma unroll
            for (int mi = 0; mi < 4; ++mi)
                #pragma unroll
                for (int ni = 0; ni < 4; ++ni)
                    acc[mi][ni] = MFMA_BF16(af[mi], bfr[ni], acc[mi][ni], 0, 0, 0);
        }
    }

    // epilogue: RoPE (pair partner in adjacent lane) + scatter
    const int mb_ = m0 + wm * 64, nbase = n0 + wn * 64;
    #pragma unroll
    for (int mi = 0; mi < 4; ++mi)
        #pragma unroll
        for (int ni = 0; ni < 4; ++ni)
            #pragma unroll
            for (int r = 0; r < 4; ++r) {
                int m = mb_ + mi * 16 + quad * 4 + r;   // C/D: row=quad*4+reg
                int n = nbase + ni * 16 + l15;          //      col=lane&15
                int b = m >> 11, s = m & 2047;
                float v = acc[mi][ni][r];
                float other = __shfl_xor(v, 1);
                if (n < 2560) {                          // rope on q and k
                    int d = n & 127;
                    int fi = s * 64 + (d >> 1);
                    float c  = fc[fi];
                    float sn = fs[fi];
                    v = (n & 1) ? (other * sn + v * c) : (v * c - other * sn);
                }
                if (n < 2048) {
                    Qr[((size_t)(b * H_ + (n >> 7)) * S_ + s) * D_ + (n & 127)] = f2b(v);
                } else if (n < 2560) {
                    int kh = (n - 2048) >> 7;
                    Kr[((size_t)(b * KVH_ + kh) * S_ + s) * D_ + (n & 127)] = f2b(v);
                } else {
                    int kh = (n - 2560) >> 7;
                    Vr[((size_t)(b * KVH_ + kh) * S_ + s) * D_ + (n & 127)] = f2b(v);
                }
            }
}

// ---------------------------------------------------------------------------
// Kernel 2: causal flash attention (unchanged from passing R8 build).
// GQA per jnp.tile: kvh = h % KVH.
// ---------------------------------------------------------------------------
__device__ __forceinline__ int vswz(int d, int k) {
    return k ^ (((d >> 3) & 3) << 3);
}

__global__ __launch_bounds__(256)
void flash_kernel(const u16* __restrict__ Qr, const u16* __restrict__ Kr,
                  const u16* __restrict__ Vr, u16* __restrict__ AO) {
    __shared__ __align__(16) u16 Ks[32][136];
    __shared__ __align__(16) u16 Vt[128][40];
    __shared__ __align__(16) u16 Ps[4][32][40];
    const int tid  = threadIdx.x;
    const int wave = tid >> 6, lane = tid & 63, l15 = lane & 15, quad = lane >> 4;
    const int qt = blockIdx.x, h = blockIdx.y, b = blockIdx.z;
    const int kvh = h & 3;
    const u16* Qb = Qr + (size_t)(b * H_ + h) * S_ * D_;
    const u16* Kb = Kr + (size_t)(b * KVH_ + kvh) * S_ * D_;
    const u16* Vb = Vr + (size_t)(b * KVH_ + kvh) * S_ * D_;
    const int q0 = qt * 128 + wave * 32;

    bf16x8 aq[2][4];
    #pragma unroll
    for (int mi = 0; mi < 2; ++mi)
        #pragma unroll
        for (int kk = 0; kk < 4; ++kk)
            aq[mi][kk] = *reinterpret_cast<const bf16x8*>(
                Qb + (size_t)(q0 + mi * 16 + l15) * D_ + kk * 32 + quad * 8);

    f32x4 o[2][8];
    const f32x4 zero4 = {0.f, 0.f, 0.f, 0.f};
    for (int i = 0; i < 2; ++i)
        for (int j = 0; j < 8; ++j) o[i][j] = zero4;
    float mst[2][4], lst[2][4];
    for (int i = 0; i < 2; ++i)
        for (int r = 0; r < 4; ++r) { mst[i][r] = -__builtin_inff(); lst[i][r] = 0.f; }

    const int ntiles = (qt + 1) * 4;
    for (int j = 0; j < ntiles; ++j) {
        const int kv0 = j * 32;
        __syncthreads();
        #pragma unroll
        for (int i = 0; i < 2; ++i) {
            int c = tid + i * 256;
            int r = c >> 4, c8 = (c & 15) * 8;
            *reinterpret_cast<uint4*>(&Ks[r][c8]) =
                *reinterpret_cast<const uint4*>(Kb + (size_t)(kv0 + r) * D_ + c8);
            bf16x8 tv = *reinterpret_cast<const bf16x8*>(Vb + (size_t)(kv0 + r) * D_ + c8);
            const u16* tp = reinterpret_cast<const u16*>(&tv);
            #pragma unroll
            for (int e = 0; e < 8; ++e) Vt[c8 + e][vswz(c8 + e, r)] = tp[e];
        }
        __syncthreads();

        f32x4 sc[2][2];
        for (int mi = 0; mi < 2; ++mi)
            for (int ni = 0; ni < 2; ++ni) sc[mi][ni] = zero4;
        #pragma unroll
        for (int kk = 0; kk < 4; ++kk) {
            bf16x8 bk0 = *reinterpret_cast<const bf16x8*>(&Ks[l15][kk * 32 + quad * 8]);
            bf16x8 bk1 = *reinterpret_cast<const bf16x8*>(&Ks[16 + l15][kk * 32 + quad * 8]);
            #pragma unroll
            for (int mi = 0; mi < 2; ++mi) {
                sc[mi][0] = MFMA_BF16(aq[mi][kk], bk0, sc[mi][0], 0, 0, 0);
                sc[mi][1] = MFMA_BF16(aq[mi][kk], bk1, sc[mi][1], 0, 0, 0);
            }
        }

        float al[2][4];
        #pragma unroll
        for (int mi = 0; mi < 2; ++mi) {
            #pragma unroll
            for (int r = 0; r < 4; ++r) {
                int qg = q0 + mi * 16 + quad * 4 + r;
                float s0 = sc[mi][0][r] * SCALE_;
                float s1 = sc[mi][1][r] * SCALE_;
                if (kv0 + l15 > qg)      s0 = -__builtin_inff();
                if (kv0 + 16 + l15 > qg) s1 = -__builtin_inff();
                float mx = fmaxf(s0, s1);
                #pragma unroll
                for (int off = 1; off < 16; off <<= 1) mx = fmaxf(mx, __shfl_xor(mx, off));
                float mnew = fmaxf(mst[mi][r], mx);
                float a  = __expf(mst[mi][r] - mnew);
                float p0 = __expf(s0 - mnew);
                float p1 = __expf(s1 - mnew);
                float sum = p0 + p1;
                #pragma unroll
                for (int off = 1; off < 16; off <<= 1) sum += __shfl_xor(sum, off);
                lst[mi][r] = lst[mi][r] * a + sum;
                mst[mi][r] = mnew;
                al[mi][r] = a;
                int prow = mi * 16 + quad * 4 + r;
                Ps[wave][prow][l15]      = f2b(p0);
                Ps[wave][prow][16 + l15] = f2b(p1);
            }
        }
        #pragma unroll
        for (int mi = 0; mi < 2; ++mi)
            #pragma unroll
            for (int ni = 0; ni < 8; ++ni)
                #pragma unroll
                for (int r = 0; r < 4; ++r) o[mi][ni][r] *= al[mi][r];

        __syncthreads();

        bf16x8 ap[2];
        #pragma unroll
        for (int mi = 0; mi < 2; ++mi)
            ap[mi] = *reinterpret_cast<const bf16x8*>(&Ps[wave][mi * 16 + l15][quad * 8]);
        #pragma unroll
        for (int ni = 0; ni < 8; ++ni) {
            int n = ni * 16 + l15;
            bf16x8 bv = *reinterpret_cast<const bf16x8*>(&Vt[n][vswz(n, quad * 8)]);
            o[0][ni] = MFMA_BF16(ap[0], bv, o[0][ni], 0, 0, 0);
            o[1][ni] = MFMA_BF16(ap[1], bv, o[1][ni], 0, 0, 0);
        }
    }

    #pragma unroll
    for (int mi = 0; mi < 2; ++mi)
        #pragma unroll
        for (int r = 0; r < 4; ++r) {
            float inv = 1.0f / lst[mi][r];
            int qg = q0 + mi * 16 + quad * 4 + r;
            size_t base = ((size_t)(b * S_ + qg)) * E_ + h * D_;
            #pragma unroll
            for (int ni = 0; ni < 8; ++ni)
                AO[base + ni * 16 + l15] = f2b(o[mi][ni][r] * inv);
        }
}

// ---------------------------------------------------------------------------
// Kernel 3: output projection, async-staged bf16 x bf16 -> f32 out.
// ---------------------------------------------------------------------------
__global__ __launch_bounds__(256)
void out_proj_gemm(const u16* __restrict__ ao, const u16* __restrict__ wob,
                   float* __restrict__ out) {
    __shared__ __align__(16) u16 As[8192];
    __shared__ __align__(16) u16 Bs[8192];
    const int tid = threadIdx.x, wave = tid >> 6, lane = tid & 63;
    const int l15 = lane & 15, quad = lane >> 4;
    const int wm = wave & 1, wn = wave >> 1;
    const int m0 = blockIdx.y * 128, n0 = blockIdx.x * 128;

    f32x4 acc[4][4];
    const f32x4 zero4 = {0.f, 0.f, 0.f, 0.f};
    for (int i = 0; i < 4; ++i)
        for (int j = 0; j < 4; ++j) acc[i][j] = zero4;

    for (int kt = 0; kt < E_; kt += 64) {
        __syncthreads();
        #pragma unroll
        for (int j = 0; j < 4; ++j) {
            int t = wave * 4 + j;
            int row = (t >> 1) * 16 + l15;
            int col = kt + (t & 1) * 32 + quad * 8;
            async16(ao  + (size_t)(m0 + row) * E_ + col, &As[t * 512]);
            async16(wob + (size_t)(n0 + row) * E_ + col, &Bs[t * 512]);
        }
        __syncthreads();
        #pragma unroll
        for (int kb = 0; kb < 2; ++kb) {
            bf16x8 af[4], bfr[4];
            #pragma unroll
            for (int i = 0; i < 4; ++i) {
                af[i]  = *reinterpret_cast<const bf16x8*>(
                    &As[(((wm * 4 + i) << 1) | kb) * 512 + lane * 8]);
                bfr[i] = *reinterpret_cast<const bf16x8*>(
                    &Bs[(((wn * 4 + i) << 1) | kb) * 512 + lane * 8]);
            }
            #pragma unroll
            for (int mi = 0; mi < 4; ++mi)
                #pragma unroll
                for (int ni = 0; ni < 4; ++ni)
                    acc[mi][ni] = MFMA_BF16(af[mi], bfr[ni], acc[mi][ni], 0, 0, 0);
        }
    }

    const int mb_ = m0 + wm * 64, nbase = n0 + wn * 64;
    #pragma unroll
    for (int mi = 0; mi < 4; ++mi)
        #pragma unroll
        for (int ni = 0; ni < 4; ++ni)
            #pragma unroll
            for (int r = 0; r < 4; ++r) {
                int m = mb_ + mi * 16 + quad * 4 + r;
                int n = nbase + ni * 16 + l15;
                out[(size_t)m * E_ + n] = acc[mi][ni][r];   // f32 output
            }
}

// ---------------------------------------------------------------------------
// Workspace (u16 offsets; total 50.33 MB = proven-safe footprint):
//   [0,        4194304): wqb (P1-P2), then wob (P3-P5)
//   [4194304, 12582912): xb  (P1-P2), then AO  (P4-P5)
//   [12582912,20971520): Qr
//   [20971520,23068672): Kr
//   [23068672,25165824): Vr
// ---------------------------------------------------------------------------
extern "C" void kernel_launch(void* const* d_in, const int* in_sizes, int n_in,
                              void* d_out, int out_size, void* d_ws, size_t ws_size,
                              hipStream_t stream) {
    const float* x  = (const float*)d_in[0];
    const float* wq = (const float*)d_in[1];
    const float* wk = (const float*)d_in[2];
    const float* wv = (const float*)d_in[3];
    const float* wo = (const float*)d_in[4];
    const float* fc = (const float*)d_in[5];
    const float* fs = (const float*)d_in[6];
    float* out = (float*)d_out;

    u16* wqb = (u16*)d_ws;                  // also wob later
    u16* xb  = wqb + 4194304;               // also AO later
    u16* Qr  = wqb + 12582912;
    u16* Kr  = wqb + 20971520;
    u16* Vr  = wqb + 23068672;
    u16* wob = wqb;
    u16* AO  = xb;

    // P1: convert x (4096 blocks) + wq (2048 blocks) to bf16
    conv_kernel<<<6144, 256, 0, stream>>>(x, xb, 4096, wq, wqb);
    // P2: fused qkv gemm + rope
    qkv_rope_gemm<<<dim3(NQKV / 128, M_ / 128), 256, 0, stream>>>(
        xb, wqb, wk, wv, fc, fs, Qr, Kr, Vr);
    // P3: convert wo (wqb region now dead)
    conv_kernel<<<2048, 256, 0, stream>>>(wo, wob, 2048, nullptr, nullptr);
    // P4: flash attention (xb region now dead -> AO)
    flash_kernel<<<dim3(S_ / 128, H_, B_), 256, 0, stream>>>(Qr, Kr, Vr, AO);
    // P5: output projection -> f32 out
    out_proj_gemm<<<dim3(E_ / 128, M_ / 128), 256, 0, stream>>>(AO, wob, out);
}

// Round 10
// 492.741 us; speedup vs baseline: 1.4363x; 1.1755x over previous
//
#include <hip/hip_runtime.h>
#include <hip/hip_bf16.h>

typedef unsigned short u16;
typedef unsigned int u32;
typedef short bf16x8 __attribute__((ext_vector_type(8)));
typedef float f32x4 __attribute__((ext_vector_type(4)));

#define MFMA_BF16 __builtin_amdgcn_mfma_f32_16x16x32_bf16

#define B_   2
#define S_   2048
#define E_   2048
#define H_   16
#define KVH_ 4
#define D_   128
#define M_   (B_ * S_)
#define NQKV 3072
#define SCALE_ 0.08838834764831845f  // 1/sqrt(128)

__device__ __forceinline__ float b2f(u16 u) {
    union { u32 i; float f; } x; x.i = ((u32)u) << 16; return x.f;
}
__device__ __forceinline__ u16 f2b(float f) {
    __hip_bfloat16 h = __float2bfloat16(f);
    return *reinterpret_cast<u16*>(&h);
}

// async 16B global->LDS: HW writes lds_base + lane*16  [m97 pattern]
__device__ __forceinline__ void async16(const u16* g, u16* l) {
    __builtin_amdgcn_global_load_lds(
        (const __attribute__((address_space(1))) void*)g,
        (__attribute__((address_space(3))) void*)l, 16, 0, 0);
}

__device__ __forceinline__ uint4 pack8(const float* p) {
    float4 a = *reinterpret_cast<const float4*>(p);
    float4 b = *reinterpret_cast<const float4*>(p + 4);
    union { uint4 v; u16 h[8]; } pk;
    pk.h[0] = f2b(a.x); pk.h[1] = f2b(a.y); pk.h[2] = f2b(a.z); pk.h[3] = f2b(a.w);
    pk.h[4] = f2b(b.x); pk.h[5] = f2b(b.y); pk.h[6] = f2b(b.z); pk.h[7] = f2b(b.w);
    return pk.v;
}

// ---------------------------------------------------------------------------
// f32 -> bf16 bulk convert, two regions per launch.
// ---------------------------------------------------------------------------
__global__ __launch_bounds__(256)
void conv_kernel(const float* __restrict__ s1, u16* __restrict__ d1, int nblk1,
                 const float* __restrict__ s2, u16* __restrict__ d2) {
    int bid = blockIdx.x;
    const float* s; u16* d; size_t base;
    if (bid < nblk1) { s = s1; d = d1; base = (size_t)bid * 2048; }
    else             { s = s2; d = d2; base = (size_t)(bid - nblk1) * 2048; }
    size_t i = base + (size_t)threadIdx.x * 8;
    *reinterpret_cast<uint4*>(d + i) = pack8(s + i);
}

// ---------------------------------------------------------------------------
// Kernel 1: fused QKV gemm_bt + RoPE epilogue (unchanged from R9).
// ---------------------------------------------------------------------------
__global__ __launch_bounds__(256)
void qkv_rope_gemm(const u16* __restrict__ xb, const u16* __restrict__ wqb,
                   const float* __restrict__ wk, const float* __restrict__ wv,
                   const float* __restrict__ fc, const float* __restrict__ fs,
                   u16* __restrict__ Qr, u16* __restrict__ Kr,
                   u16* __restrict__ Vr) {
    __shared__ __align__(16) u16 As[8192];
    __shared__ __align__(16) u16 Bs[8192];
    const int tid = threadIdx.x, wave = tid >> 6, lane = tid & 63;
    const int l15 = lane & 15, quad = lane >> 4;
    const int wm = wave & 1, wn = wave >> 1;
    const int m0 = blockIdx.y * 128, n0 = blockIdx.x * 128;

    const bool qpart = (n0 < 2048);
    const float* wf32 = nullptr; int nb = 0;
    if (n0 >= 2560)      { wf32 = wv; nb = n0 - 2560; }
    else if (n0 >= 2048) { wf32 = wk; nb = n0 - 2048; }

    f32x4 acc[4][4];
    const f32x4 zero4 = {0.f, 0.f, 0.f, 0.f};
    for (int i = 0; i < 4; ++i)
        for (int j = 0; j < 4; ++j) acc[i][j] = zero4;

    for (int kt = 0; kt < E_; kt += 64) {
        __syncthreads();
        #pragma unroll
        for (int j = 0; j < 4; ++j) {
            int t = wave * 4 + j;
            int row = m0 + (t >> 1) * 16 + l15;
            int col = kt + (t & 1) * 32 + quad * 8;
            async16(xb + (size_t)row * E_ + col, &As[t * 512]);
        }
        if (qpart) {
            #pragma unroll
            for (int j = 0; j < 4; ++j) {
                int t = wave * 4 + j;
                int row = n0 + (t >> 1) * 16 + l15;
                int col = kt + (t & 1) * 32 + quad * 8;
                async16(wqb + (size_t)row * E_ + col, &Bs[t * 512]);
            }
        } else {
            #pragma unroll
            for (int p = 0; p < 4; ++p) {
                int t = p * 4 + wave;
                int row = nb + (t >> 1) * 16 + l15;
                int col = kt + (t & 1) * 32 + quad * 8;
                *reinterpret_cast<uint4*>(&Bs[t * 512 + lane * 8]) =
                    pack8(wf32 + (size_t)row * E_ + col);
            }
        }
        __syncthreads();
        #pragma unroll
        for (int kb = 0; kb < 2; ++kb) {
            bf16x8 af[4], bfr[4];
            #pragma unroll
            for (int i = 0; i < 4; ++i) {
                af[i]  = *reinterpret_cast<const bf16x8*>(
                    &As[(((wm * 4 + i) << 1) | kb) * 512 + lane * 8]);
                bfr[i] = *reinterpret_cast<const bf16x8*>(
                    &Bs[(((wn * 4 + i) << 1) | kb) * 512 + lane * 8]);
            }
            #pragma unroll
            for (int mi = 0; mi < 4; ++mi)
                #pragma unroll
                for (int ni = 0; ni < 4; ++ni)
                    acc[mi][ni] = MFMA_BF16(af[mi], bfr[ni], acc[mi][ni], 0, 0, 0);
        }
    }

    const int mb_ = m0 + wm * 64, nbase = n0 + wn * 64;
    #pragma unroll
    for (int mi = 0; mi < 4; ++mi)
        #pragma unroll
        for (int ni = 0; ni < 4; ++ni)
            #pragma unroll
            for (int r = 0; r < 4; ++r) {
                int m = mb_ + mi * 16 + quad * 4 + r;
                int n = nbase + ni * 16 + l15;
                int b = m >> 11, s = m & 2047;
                float v = acc[mi][ni][r];
                float other = __shfl_xor(v, 1);
                if (n < 2560) {
                    int d = n & 127;
                    int fi = s * 64 + (d >> 1);
                    float c  = fc[fi];
                    float sn = fs[fi];
                    v = (n & 1) ? (other * sn + v * c) : (v * c - other * sn);
                }
                if (n < 2048) {
                    Qr[((size_t)(b * H_ + (n >> 7)) * S_ + s) * D_ + (n & 127)] = f2b(v);
                } else if (n < 2560) {
                    int kh = (n - 2048) >> 7;
                    Kr[((size_t)(b * KVH_ + kh) * S_ + s) * D_ + (n & 127)] = f2b(v);
                } else {
                    int kh = (n - 2560) >> 7;
                    Vr[((size_t)(b * KVH_ + kh) * S_ + s) * D_ + (n & 127)] = f2b(v);
                }
            }
}

// ---------------------------------------------------------------------------
// Kernel 1.7: V transpose per (b,kvh): Vr[s][d] -> VrT[d][s].
// grid (S/64, D/64, B*KVH), 256 thr, 64x64 LDS tile.
// ---------------------------------------------------------------------------
__global__ __launch_bounds__(256)
void transpose_v(const u16* __restrict__ Vr, u16* __restrict__ VrT) {
    __shared__ u16 t[64][72];
    const int tid = threadIdx.x;
    const int s0 = blockIdx.x * 64, d0 = blockIdx.y * 64, g = blockIdx.z;
    const u16* src = Vr + (size_t)g * S_ * D_;
    u16* dst = VrT + (size_t)g * D_ * S_;
    #pragma unroll
    for (int i = 0; i < 2; ++i) {
        int c = tid + i * 256;
        int r = c >> 3, cc = (c & 7) * 8;
        *reinterpret_cast<uint4*>(&t[r][cc]) =
            *reinterpret_cast<const uint4*>(src + (size_t)(s0 + r) * D_ + d0 + cc);
    }
    __syncthreads();
    #pragma unroll
    for (int i = 0; i < 2; ++i) {
        int c = tid + i * 256;
        int r = c >> 3, cc = (c & 7) * 8;
        u16 tmp[8];
        #pragma unroll
        for (int e = 0; e < 8; ++e) tmp[e] = t[cc + e][r];
        *reinterpret_cast<uint4*>(dst + (size_t)(d0 + r) * S_ + s0 + cc) =
            *reinterpret_cast<const uint4*>(tmp);
    }
}

// ---------------------------------------------------------------------------
// Kernel 2: transposed causal flash attention.
// Computes S^T = K Q^T and O^T = V^T P^T: each lane owns ONE q column
// (l15) -> scalar m/l state, 2-shuffle reductions; P C->B-frag conversion
// in-register (2 shfl + select per elem); K and V^T staged fragment-major
// via global_load_lds (conflict-free).  512 thr = 8 waves x 16 q rows;
// kv tile 64.  GQA per jnp.tile: kvh = h % KVH.
// ---------------------------------------------------------------------------
__global__ __launch_bounds__(512, 4)
void flash2(const u16* __restrict__ Qr, const u16* __restrict__ Kr,
            const u16* __restrict__ VrT, u16* __restrict__ AO) {
    __shared__ __align__(16) u16 Ks[64 * 128];   // frag t=kb*4+kk: 16 x 1KB
    __shared__ __align__(16) u16 Vs[128 * 64];   // frag t=mi*2+kf: 16 x 1KB
    const int tid = threadIdx.x, wave = tid >> 6, lane = tid & 63;
    const int l15 = lane & 15, quad = lane >> 4;
    const int qt = blockIdx.x, h = blockIdx.y, b = blockIdx.z;
    const int kvh = h & 3;                        // jnp.tile mapping
    const u16* Qb = Qr + (size_t)(b * H_ + h) * S_ * D_;
    const u16* Kb = Kr + (size_t)(b * KVH_ + kvh) * S_ * D_;
    const u16* Vb = VrT + (size_t)(b * KVH_ + kvh) * D_ * S_;
    const int q0 = qt * 128 + wave * 16;
    const int qg = q0 + l15;                      // this lane's q row

    // Q as B-operand (n=q=l15, k=e=quad*8+j), register-resident
    bf16x8 bq[4];
    #pragma unroll
    for (int kk = 0; kk < 4; ++kk)
        bq[kk] = *reinterpret_cast<const bf16x8*>(
            Qb + (size_t)qg * D_ + kk * 32 + quad * 8);

    f32x4 o[8];
    const f32x4 zero4 = {0.f, 0.f, 0.f, 0.f};
    #pragma unroll
    for (int i = 0; i < 8; ++i) o[i] = zero4;
    float m_i = -__builtin_inff(), l_i = 0.f;

    // per-wave staging: frags t0,t1 for both K and V^T
    const int t0 = wave * 2, t1 = t0 + 1;
    const u16* kp0 = Kb + (size_t)((t0 >> 2) * 16 + l15) * D_ + (t0 & 3) * 32 + quad * 8;
    const u16* kp1 = Kb + (size_t)((t1 >> 2) * 16 + l15) * D_ + (t1 & 3) * 32 + quad * 8;
    const u16* vp0 = Vb + (size_t)((t0 >> 1) * 16 + l15) * S_ + (t0 & 1) * 32 + quad * 8;
    const u16* vp1 = Vb + (size_t)((t1 >> 1) * 16 + l15) * S_ + (t1 & 1) * 32 + quad * 8;

    const int ntiles = (qt + 1) * 2;
    for (int j = 0; j < ntiles; ++j) {
        const int kv0 = j * 64;
        __syncthreads();                          // protect prev-tile LDS reads
        async16(kp0, &Ks[t0 * 512]);
        async16(kp1, &Ks[t1 * 512]);
        async16(vp0, &Vs[t0 * 512]);
        async16(vp1, &Vs[t1 * 512]);
        __syncthreads();                          // drains vmcnt before barrier

        // S^T[kv 64][q 16]
        f32x4 st[4];
        #pragma unroll
        for (int kb = 0; kb < 4; ++kb) st[kb] = zero4;
        #pragma unroll
        for (int kk = 0; kk < 4; ++kk)
            #pragma unroll
            for (int kb = 0; kb < 4; ++kb) {
                bf16x8 ak = *reinterpret_cast<const bf16x8*>(
                    &Ks[(kb * 4 + kk) * 512 + lane * 8]);
                st[kb] = MFMA_BF16(ak, bq[kk], st[kb], 0, 0, 0);
            }

        // online softmax (lane owns one q column; kv spread over kb,reg,quad)
        float mx = -__builtin_inff();
        if (j >= 2 * qt) {                        // diagonal tiles: mask
            #pragma unroll
            for (int kb = 0; kb < 4; ++kb)
                #pragma unroll
                for (int r = 0; r < 4; ++r) {
                    float s = st[kb][r] * SCALE_;
                    if (kv0 + kb * 16 + quad * 4 + r > qg) s = -__builtin_inff();
                    st[kb][r] = s;
                    mx = fmaxf(mx, s);
                }
        } else {
            #pragma unroll
            for (int kb = 0; kb < 4; ++kb)
                #pragma unroll
                for (int r = 0; r < 4; ++r) {
                    float s = st[kb][r] * SCALE_;
                    st[kb][r] = s;
                    mx = fmaxf(mx, s);
                }
        }
        mx = fmaxf(mx, __shfl_xor(mx, 16));
        mx = fmaxf(mx, __shfl_xor(mx, 32));
        float mnew = fmaxf(m_i, mx);
        float a = __expf(m_i - mnew);
        float sum = 0.f;
        #pragma unroll
        for (int kb = 0; kb < 4; ++kb)
            #pragma unroll
            for (int r = 0; r < 4; ++r) {
                float p = __expf(st[kb][r] - mnew);
                st[kb][r] = p;
                sum += p;
            }
        sum += __shfl_xor(sum, 16);
        sum += __shfl_xor(sum, 32);
        l_i = l_i * a + sum;
        m_i = mnew;
        #pragma unroll
        for (int mi = 0; mi < 8; ++mi)
            #pragma unroll
            for (int r = 0; r < 4; ++r) o[mi][r] *= a;

        // P C-layout -> B-frag (n=q=l15, k=kv=quad*8+j2) via shuffles; PV
        #pragma unroll
        for (int kf = 0; kf < 2; ++kf) {
            bf16x8 bp;
            u16* bh = (u16*)&bp;
            #pragma unroll
            for (int j2 = 0; j2 < 8; ++j2) {
                int src = ((quad & 1) * 2 + (j2 >> 2)) * 16 + l15;
                float v0 = __shfl(st[kf * 2 + 0][j2 & 3], src);
                float v1 = __shfl(st[kf * 2 + 1][j2 & 3], src);
                bh[j2] = f2b((lane >= 32) ? v1 : v0);
            }
            #pragma unroll
            for (int mi = 0; mi < 8; ++mi) {
                bf16x8 av = *reinterpret_cast<const bf16x8*>(
                    &Vs[(mi * 2 + kf) * 512 + lane * 8]);
                o[mi] = MFMA_BF16(av, bp, o[mi], 0, 0, 0);
            }
        }
        kp0 += 64 * D_; kp1 += 64 * D_; vp0 += 64; vp1 += 64;
    }

    // epilogue: O^T[d][q], lane holds d = mi*16+quad*4+r for its q
    float inv = 1.0f / l_i;
    size_t base = ((size_t)(b * S_ + qg)) * E_ + h * D_;
    #pragma unroll
    for (int mi = 0; mi < 8; ++mi) {
        u16 w[4];
        #pragma unroll
        for (int r = 0; r < 4; ++r) w[r] = f2b(o[mi][r] * inv);
        *reinterpret_cast<uint2*>(AO + base + mi * 16 + quad * 4) =
            *reinterpret_cast<const uint2*>(w);
    }
}

// ---------------------------------------------------------------------------
// Kernel 3: output projection (unchanged from R9), f32 out.
// ---------------------------------------------------------------------------
__global__ __launch_bounds__(256)
void out_proj_gemm(const u16* __restrict__ ao, const u16* __restrict__ wob,
                   float* __restrict__ out) {
    __shared__ __align__(16) u16 As[8192];
    __shared__ __align__(16) u16 Bs[8192];
    const int tid = threadIdx.x, wave = tid >> 6, lane = tid & 63;
    const int l15 = lane & 15, quad = lane >> 4;
    const int wm = wave & 1, wn = wave >> 1;
    const int m0 = blockIdx.y * 128, n0 = blockIdx.x * 128;

    f32x4 acc[4][4];
    const f32x4 zero4 = {0.f, 0.f, 0.f, 0.f};
    for (int i = 0; i < 4; ++i)
        for (int j = 0; j < 4; ++j) acc[i][j] = zero4;

    for (int kt = 0; kt < E_; kt += 64) {
        __syncthreads();
        #pragma unroll
        for (int j = 0; j < 4; ++j) {
            int t = wave * 4 + j;
            int row = (t >> 1) * 16 + l15;
            int col = kt + (t & 1) * 32 + quad * 8;
            async16(ao  + (size_t)(m0 + row) * E_ + col, &As[t * 512]);
            async16(wob + (size_t)(n0 + row) * E_ + col, &Bs[t * 512]);
        }
        __syncthreads();
        #pragma unroll
        for (int kb = 0; kb < 2; ++kb) {
            bf16x8 af[4], bfr[4];
            #pragma unroll
            for (int i = 0; i < 4; ++i) {
                af[i]  = *reinterpret_cast<const bf16x8*>(
                    &As[(((wm * 4 + i) << 1) | kb) * 512 + lane * 8]);
                bfr[i] = *reinterpret_cast<const bf16x8*>(
                    &Bs[(((wn * 4 + i) << 1) | kb) * 512 + lane * 8]);
            }
            #pragma unroll
            for (int mi = 0; mi < 4; ++mi)
                #pragma unroll
                for (int ni = 0; ni < 4; ++ni)
                    acc[mi][ni] = MFMA_BF16(af[mi], bfr[ni], acc[mi][ni], 0, 0, 0);
        }
    }

    const int mb_ = m0 + wm * 64, nbase = n0 + wn * 64;
    #pragma unroll
    for (int mi = 0; mi < 4; ++mi)
        #pragma unroll
        for (int ni = 0; ni < 4; ++ni)
            #pragma unroll
            for (int r = 0; r < 4; ++r) {
                int m = mb_ + mi * 16 + quad * 4 + r;
                int n = nbase + ni * 16 + l15;
                out[(size_t)m * E_ + n] = acc[mi][ni][r];
            }
}

// ---------------------------------------------------------------------------
// Workspace (u16 offsets; 50.33 MB total, proven-safe):
//   [0,        4194304): wqb (P1-P2) -> VrT (P3-P4) -> wob (P5-P6)
//   [4194304, 12582912): xb  (P1-P2) -> AO  (P4-P6)
//   [12582912,20971520): Qr
//   [20971520,23068672): Kr
//   [23068672,25165824): Vr
// ---------------------------------------------------------------------------
extern "C" void kernel_launch(void* const* d_in, const int* in_sizes, int n_in,
                              void* d_out, int out_size, void* d_ws, size_t ws_size,
                              hipStream_t stream) {
    const float* x  = (const float*)d_in[0];
    const float* wq = (const float*)d_in[1];
    const float* wk = (const float*)d_in[2];
    const float* wv = (const float*)d_in[3];
    const float* wo = (const float*)d_in[4];
    const float* fc = (const float*)d_in[5];
    const float* fs = (const float*)d_in[6];
    float* out = (float*)d_out;

    u16* wqb = (u16*)d_ws;
    u16* xb  = wqb + 4194304;
    u16* Qr  = wqb + 12582912;
    u16* Kr  = wqb + 20971520;
    u16* Vr  = wqb + 23068672;
    u16* VrT = wqb;          // after qkv (wqb dead)
    u16* wob = wqb;          // after flash (VrT dead)
    u16* AO  = xb;           // after qkv (xb dead)

    conv_kernel<<<6144, 256, 0, stream>>>(x, xb, 4096, wq, wqb);
    qkv_rope_gemm<<<dim3(NQKV / 128, M_ / 128), 256, 0, stream>>>(
        xb, wqb, wk, wv, fc, fs, Qr, Kr, Vr);
    transpose_v<<<dim3(S_ / 64, D_ / 64, B_ * KVH_), 256, 0, stream>>>(Vr, VrT);
    flash2<<<dim3(S_ / 128, H_, B_), 512, 0, stream>>>(Qr, Kr, VrT, AO);
    conv_kernel<<<2048, 256, 0, stream>>>(wo, wob, 2048, nullptr, nullptr);
    out_proj_gemm<<<dim3(E_ / 128, M_ / 128), 256, 0, stream>>>(AO, wob, out);
}

// Round 11
// 465.128 us; speedup vs baseline: 1.5215x; 1.0594x over previous
//
#include <hip/hip_runtime.h>
#include <hip/hip_bf16.h>

typedef unsigned short u16;
typedef unsigned int u32;
typedef short bf16x8 __attribute__((ext_vector_type(8)));
typedef float f32x4 __attribute__((ext_vector_type(4)));

#define MFMA_BF16 __builtin_amdgcn_mfma_f32_16x16x32_bf16

#define B_   2
#define S_   2048
#define E_   2048
#define H_   16
#define KVH_ 4
#define D_   128
#define M_   (B_ * S_)
#define NQKV 3072
#define SCALE_ 0.08838834764831845f  // 1/sqrt(128)

__device__ __forceinline__ float b2f(u16 u) {
    union { u32 i; float f; } x; x.i = ((u32)u) << 16; return x.f;
}
__device__ __forceinline__ u16 f2b(float f) {
    __hip_bfloat16 h = __float2bfloat16(f);
    return *reinterpret_cast<u16*>(&h);
}

// async 16B global->LDS: HW writes lds_base + lane*16  [m97 pattern]
__device__ __forceinline__ void async16(const u16* g, u16* l) {
    __builtin_amdgcn_global_load_lds(
        (const __attribute__((address_space(1))) void*)g,
        (__attribute__((address_space(3))) void*)l, 16, 0, 0);
}

__device__ __forceinline__ uint4 pack8(const float* p) {
    float4 a = *reinterpret_cast<const float4*>(p);
    float4 b = *reinterpret_cast<const float4*>(p + 4);
    union { uint4 v; u16 h[8]; } pk;
    pk.h[0] = f2b(a.x); pk.h[1] = f2b(a.y); pk.h[2] = f2b(a.z); pk.h[3] = f2b(a.w);
    pk.h[4] = f2b(b.x); pk.h[5] = f2b(b.y); pk.h[6] = f2b(b.z); pk.h[7] = f2b(b.w);
    return pk.v;
}

// ---------------------------------------------------------------------------
// f32 -> bf16 bulk convert, up to 4 regions per launch (2048 elems/block).
// ---------------------------------------------------------------------------
__global__ __launch_bounds__(256)
void conv4(const float* __restrict__ s0, u16* __restrict__ d0, int n0,
           const float* __restrict__ s1, u16* __restrict__ d1, int n1,
           const float* __restrict__ s2, u16* __restrict__ d2, int n2,
           const float* __restrict__ s3, u16* __restrict__ d3) {
    int bid = blockIdx.x;
    const float* s; u16* d; size_t base;
    if (bid < n0)                { s = s0; d = d0; base = (size_t)bid * 2048; }
    else if (bid < n0 + n1)      { s = s1; d = d1; base = (size_t)(bid - n0) * 2048; }
    else if (bid < n0 + n1 + n2) { s = s2; d = d2; base = (size_t)(bid - n0 - n1) * 2048; }
    else                         { s = s3; d = d3; base = (size_t)(bid - n0 - n1 - n2) * 2048; }
    size_t i = base + (size_t)threadIdx.x * 8;
    *reinterpret_cast<uint4*>(d + i) = pack8(s + i);
}

// ---------------------------------------------------------------------------
// Kernel 1: fused QKV gemm_bt + RoPE epilogue.  ALL operands bf16 now:
// every tile staged with global_load_lds width-16, fragment-major LDS
// (conflict-free, lane-exact).  128x128 tile, BK=64.
// ---------------------------------------------------------------------------
__global__ __launch_bounds__(256)
void qkv_rope_gemm(const u16* __restrict__ xb, const u16* __restrict__ wqb,
                   const u16* __restrict__ wkb, const u16* __restrict__ wvb,
                   const float* __restrict__ fc, const float* __restrict__ fs,
                   u16* __restrict__ Qr, u16* __restrict__ Kr,
                   u16* __restrict__ Vr) {
    __shared__ __align__(16) u16 As[8192];
    __shared__ __align__(16) u16 Bs[8192];
    const int tid = threadIdx.x, wave = tid >> 6, lane = tid & 63;
    const int l15 = lane & 15, quad = lane >> 4;
    const int wm = wave & 1, wn = wave >> 1;
    const int m0 = blockIdx.y * 128, n0 = blockIdx.x * 128;

    // select weight buffer; tile rows are local to that buffer
    const u16* wsel;
    if (n0 < 2048)      wsel = wqb + (size_t)n0 * E_;
    else if (n0 < 2560) wsel = wkb + (size_t)(n0 - 2048) * E_;
    else                wsel = wvb + (size_t)(n0 - 2560) * E_;

    f32x4 acc[4][4];
    const f32x4 zero4 = {0.f, 0.f, 0.f, 0.f};
    for (int i = 0; i < 4; ++i)
        for (int j = 0; j < 4; ++j) acc[i][j] = zero4;

    for (int kt = 0; kt < E_; kt += 64) {
        __syncthreads();
        #pragma unroll
        for (int j = 0; j < 4; ++j) {
            int t = wave * 4 + j;
            int row = (t >> 1) * 16 + l15;
            int col = kt + (t & 1) * 32 + quad * 8;
            async16(xb + (size_t)(m0 + row) * E_ + col, &As[t * 512]);
            async16(wsel + (size_t)row * E_ + col, &Bs[t * 512]);
        }
        __syncthreads();
        #pragma unroll
        for (int kb = 0; kb < 2; ++kb) {
            bf16x8 af[4], bfr[4];
            #pragma unroll
            for (int i = 0; i < 4; ++i) {
                af[i]  = *reinterpret_cast<const bf16x8*>(
                    &As[(((wm * 4 + i) << 1) | kb) * 512 + lane * 8]);
                bfr[i] = *reinterpret_cast<const bf16x8*>(
                    &Bs[(((wn * 4 + i) << 1) | kb) * 512 + lane * 8]);
            }
            #pragma unroll
            for (int mi = 0; mi < 4; ++mi)
                #pragma unroll
                for (int ni = 0; ni < 4; ++ni)
                    acc[mi][ni] = MFMA_BF16(af[mi], bfr[ni], acc[mi][ni], 0, 0, 0);
        }
    }

    // epilogue: RoPE (pair partner in adjacent lane) + scatter
    const int mb_ = m0 + wm * 64, nbase = n0 + wn * 64;
    #pragma unroll
    for (int mi = 0; mi < 4; ++mi)
        #pragma unroll
        for (int ni = 0; ni < 4; ++ni)
            #pragma unroll
            for (int r = 0; r < 4; ++r) {
                int m = mb_ + mi * 16 + quad * 4 + r;   // C/D: row=quad*4+reg
                int n = nbase + ni * 16 + l15;          //      col=lane&15
                int b = m >> 11, s = m & 2047;
                float v = acc[mi][ni][r];
                float other = __shfl_xor(v, 1);
                if (n < 2560) {                          // rope on q and k
                    int d = n & 127;
                    int fi = s * 64 + (d >> 1);
                    float c  = fc[fi];
                    float sn = fs[fi];
                    v = (n & 1) ? (other * sn + v * c) : (v * c - other * sn);
                }
                if (n < 2048) {
                    Qr[((size_t)(b * H_ + (n >> 7)) * S_ + s) * D_ + (n & 127)] = f2b(v);
                } else if (n < 2560) {
                    int kh = (n - 2048) >> 7;
                    Kr[((size_t)(b * KVH_ + kh) * S_ + s) * D_ + (n & 127)] = f2b(v);
                } else {
                    int kh = (n - 2560) >> 7;
                    Vr[((size_t)(b * KVH_ + kh) * S_ + s) * D_ + (n & 127)] = f2b(v);
                }
            }
}

// ---------------------------------------------------------------------------
// Kernel 1.7: V transpose per (b,kvh): Vr[s][d] -> VrT[d][s].
// ---------------------------------------------------------------------------
__global__ __launch_bounds__(256)
void transpose_v(const u16* __restrict__ Vr, u16* __restrict__ VrT) {
    __shared__ u16 t[64][72];
    const int tid = threadIdx.x;
    const int s0 = blockIdx.x * 64, d0 = blockIdx.y * 64, g = blockIdx.z;
    const u16* src = Vr + (size_t)g * S_ * D_;
    u16* dst = VrT + (size_t)g * D_ * S_;
    #pragma unroll
    for (int i = 0; i < 2; ++i) {
        int c = tid + i * 256;
        int r = c >> 3, cc = (c & 7) * 8;
        *reinterpret_cast<uint4*>(&t[r][cc]) =
            *reinterpret_cast<const uint4*>(src + (size_t)(s0 + r) * D_ + d0 + cc);
    }
    __syncthreads();
    #pragma unroll
    for (int i = 0; i < 2; ++i) {
        int c = tid + i * 256;
        int r = c >> 3, cc = (c & 7) * 8;
        u16 tmp[8];
        #pragma unroll
        for (int e = 0; e < 8; ++e) tmp[e] = t[cc + e][r];
        *reinterpret_cast<uint4*>(dst + (size_t)(d0 + r) * S_ + s0 + cc) =
            *reinterpret_cast<const uint4*>(tmp);
    }
}

// ---------------------------------------------------------------------------
// Kernel 2: transposed causal flash attention (unchanged from R10).
// ---------------------------------------------------------------------------
__global__ __launch_bounds__(512, 4)
void flash2(const u16* __restrict__ Qr, const u16* __restrict__ Kr,
            const u16* __restrict__ VrT, u16* __restrict__ AO) {
    __shared__ __align__(16) u16 Ks[64 * 128];
    __shared__ __align__(16) u16 Vs[128 * 64];
    const int tid = threadIdx.x, wave = tid >> 6, lane = tid & 63;
    const int l15 = lane & 15, quad = lane >> 4;
    const int qt = blockIdx.x, h = blockIdx.y, b = blockIdx.z;
    const int kvh = h & 3;                        // jnp.tile mapping
    const u16* Qb = Qr + (size_t)(b * H_ + h) * S_ * D_;
    const u16* Kb = Kr + (size_t)(b * KVH_ + kvh) * S_ * D_;
    const u16* Vb = VrT + (size_t)(b * KVH_ + kvh) * D_ * S_;
    const int q0 = qt * 128 + wave * 16;
    const int qg = q0 + l15;

    bf16x8 bq[4];
    #pragma unroll
    for (int kk = 0; kk < 4; ++kk)
        bq[kk] = *reinterpret_cast<const bf16x8*>(
            Qb + (size_t)qg * D_ + kk * 32 + quad * 8);

    f32x4 o[8];
    const f32x4 zero4 = {0.f, 0.f, 0.f, 0.f};
    #pragma unroll
    for (int i = 0; i < 8; ++i) o[i] = zero4;
    float m_i = -__builtin_inff(), l_i = 0.f;

    const int t0 = wave * 2, t1 = t0 + 1;
    const u16* kp0 = Kb + (size_t)((t0 >> 2) * 16 + l15) * D_ + (t0 & 3) * 32 + quad * 8;
    const u16* kp1 = Kb + (size_t)((t1 >> 2) * 16 + l15) * D_ + (t1 & 3) * 32 + quad * 8;
    const u16* vp0 = Vb + (size_t)((t0 >> 1) * 16 + l15) * S_ + (t0 & 1) * 32 + quad * 8;
    const u16* vp1 = Vb + (size_t)((t1 >> 1) * 16 + l15) * S_ + (t1 & 1) * 32 + quad * 8;

    const int ntiles = (qt + 1) * 2;
    for (int j = 0; j < ntiles; ++j) {
        const int kv0 = j * 64;
        __syncthreads();
        async16(kp0, &Ks[t0 * 512]);
        async16(kp1, &Ks[t1 * 512]);
        async16(vp0, &Vs[t0 * 512]);
        async16(vp1, &Vs[t1 * 512]);
        __syncthreads();

        f32x4 st[4];
        #pragma unroll
        for (int kb = 0; kb < 4; ++kb) st[kb] = zero4;
        #pragma unroll
        for (int kk = 0; kk < 4; ++kk)
            #pragma unroll
            for (int kb = 0; kb < 4; ++kb) {
                bf16x8 ak = *reinterpret_cast<const bf16x8*>(
                    &Ks[(kb * 4 + kk) * 512 + lane * 8]);
                st[kb] = MFMA_BF16(ak, bq[kk], st[kb], 0, 0, 0);
            }

        float mx = -__builtin_inff();
        if (j >= 2 * qt) {
            #pragma unroll
            for (int kb = 0; kb < 4; ++kb)
                #pragma unroll
                for (int r = 0; r < 4; ++r) {
                    float s = st[kb][r] * SCALE_;
                    if (kv0 + kb * 16 + quad * 4 + r > qg) s = -__builtin_inff();
                    st[kb][r] = s;
                    mx = fmaxf(mx, s);
                }
        } else {
            #pragma unroll
            for (int kb = 0; kb < 4; ++kb)
                #pragma unroll
                for (int r = 0; r < 4; ++r) {
                    float s = st[kb][r] * SCALE_;
                    st[kb][r] = s;
                    mx = fmaxf(mx, s);
                }
        }
        mx = fmaxf(mx, __shfl_xor(mx, 16));
        mx = fmaxf(mx, __shfl_xor(mx, 32));
        float mnew = fmaxf(m_i, mx);
        float a = __expf(m_i - mnew);
        float sum = 0.f;
        #pragma unroll
        for (int kb = 0; kb < 4; ++kb)
            #pragma unroll
            for (int r = 0; r < 4; ++r) {
                float p = __expf(st[kb][r] - mnew);
                st[kb][r] = p;
                sum += p;
            }
        sum += __shfl_xor(sum, 16);
        sum += __shfl_xor(sum, 32);
        l_i = l_i * a + sum;
        m_i = mnew;
        #pragma unroll
        for (int mi = 0; mi < 8; ++mi)
            #pragma unroll
            for (int r = 0; r < 4; ++r) o[mi][r] *= a;

        #pragma unroll
        for (int kf = 0; kf < 2; ++kf) {
            bf16x8 bp;
            u16* bh = (u16*)&bp;
            #pragma unroll
            for (int j2 = 0; j2 < 8; ++j2) {
                int src = ((quad & 1) * 2 + (j2 >> 2)) * 16 + l15;
                float v0 = __shfl(st[kf * 2 + 0][j2 & 3], src);
                float v1 = __shfl(st[kf * 2 + 1][j2 & 3], src);
                bh[j2] = f2b((lane >= 32) ? v1 : v0);
            }
            #pragma unroll
            for (int mi = 0; mi < 8; ++mi) {
                bf16x8 av = *reinterpret_cast<const bf16x8*>(
                    &Vs[(mi * 2 + kf) * 512 + lane * 8]);
                o[mi] = MFMA_BF16(av, bp, o[mi], 0, 0, 0);
            }
        }
        kp0 += 64 * D_; kp1 += 64 * D_; vp0 += 64; vp1 += 64;
    }

    float inv = 1.0f / l_i;
    size_t base = ((size_t)(b * S_ + qg)) * E_ + h * D_;
    #pragma unroll
    for (int mi = 0; mi < 8; ++mi) {
        u16 w[4];
        #pragma unroll
        for (int r = 0; r < 4; ++r) w[r] = f2b(o[mi][r] * inv);
        *reinterpret_cast<uint2*>(AO + base + mi * 16 + quad * 4) =
            *reinterpret_cast<const uint2*>(w);
    }
}

// ---------------------------------------------------------------------------
// Kernel 3: output projection (unchanged), f32 out.
// ---------------------------------------------------------------------------
__global__ __launch_bounds__(256)
void out_proj_gemm(const u16* __restrict__ ao, const u16* __restrict__ wob,
                   float* __restrict__ out) {
    __shared__ __align__(16) u16 As[8192];
    __shared__ __align__(16) u16 Bs[8192];
    const int tid = threadIdx.x, wave = tid >> 6, lane = tid & 63;
    const int l15 = lane & 15, quad = lane >> 4;
    const int wm = wave & 1, wn = wave >> 1;
    const int m0 = blockIdx.y * 128, n0 = blockIdx.x * 128;

    f32x4 acc[4][4];
    const f32x4 zero4 = {0.f, 0.f, 0.f, 0.f};
    for (int i = 0; i < 4; ++i)
        for (int j = 0; j < 4; ++j) acc[i][j] = zero4;

    for (int kt = 0; kt < E_; kt += 64) {
        __syncthreads();
        #pragma unroll
        for (int j = 0; j < 4; ++j) {
            int t = wave * 4 + j;
            int row = (t >> 1) * 16 + l15;
            int col = kt + (t & 1) * 32 + quad * 8;
            async16(ao  + (size_t)(m0 + row) * E_ + col, &As[t * 512]);
            async16(wob + (size_t)(n0 + row) * E_ + col, &Bs[t * 512]);
        }
        __syncthreads();
        #pragma unroll
        for (int kb = 0; kb < 2; ++kb) {
            bf16x8 af[4], bfr[4];
            #pragma unroll
            for (int i = 0; i < 4; ++i) {
                af[i]  = *reinterpret_cast<const bf16x8*>(
                    &As[(((wm * 4 + i) << 1) | kb) * 512 + lane * 8]);
                bfr[i] = *reinterpret_cast<const bf16x8*>(
                    &Bs[(((wn * 4 + i) << 1) | kb) * 512 + lane * 8]);
            }
            #pragma unroll
            for (int mi = 0; mi < 4; ++mi)
                #pragma unroll
                for (int ni = 0; ni < 4; ++ni)
                    acc[mi][ni] = MFMA_BF16(af[mi], bfr[ni], acc[mi][ni], 0, 0, 0);
        }
    }

    const int mb_ = m0 + wm * 64, nbase = n0 + wn * 64;
    #pragma unroll
    for (int mi = 0; mi < 4; ++mi)
        #pragma unroll
        for (int ni = 0; ni < 4; ++ni)
            #pragma unroll
            for (int r = 0; r < 4; ++r) {
                int m = mb_ + mi * 16 + quad * 4 + r;
                int n = nbase + ni * 16 + l15;
                out[(size_t)m * E_ + n] = acc[mi][ni][r];
            }
}

// ---------------------------------------------------------------------------
// Workspace (u16 offsets; 50.33 MB, proven-safe):
//   [0,        4194304): wqb (conv->qkv) -> VrT (transpose->flash) -> wob
//   [4194304, 12582912): xb  (conv->qkv) -> AO  (flash->out_proj)
//   [12582912,20971520): Qr
//   [20971520,23068672): Kr
//   [23068672,25165824): Vr
// d_out scratch (33.5 MB, rewritten entirely by out_proj at the end):
//   [0, 1048576) u16:  wkb     [1048576, 2097152) u16:  wvb
// ---------------------------------------------------------------------------
extern "C" void kernel_launch(void* const* d_in, const int* in_sizes, int n_in,
                              void* d_out, int out_size, void* d_ws, size_t ws_size,
                              hipStream_t stream) {
    const float* x  = (const float*)d_in[0];
    const float* wq = (const float*)d_in[1];
    const float* wk = (const float*)d_in[2];
    const float* wv = (const float*)d_in[3];
    const float* wo = (const float*)d_in[4];
    const float* fc = (const float*)d_in[5];
    const float* fs = (const float*)d_in[6];
    float* out = (float*)d_out;

    u16* wqb = (u16*)d_ws;
    u16* xb  = wqb + 4194304;
    u16* Qr  = wqb + 12582912;
    u16* Kr  = wqb + 20971520;
    u16* Vr  = wqb + 23068672;
    u16* VrT = wqb;          // after qkv (wqb dead)
    u16* wob = wqb;          // after flash (VrT dead)
    u16* AO  = xb;           // after qkv (xb dead)
    u16* wkb = (u16*)d_out;              // d_out scratch until out_proj
    u16* wvb = wkb + 1048576;

    // P1: convert x, wq, wk, wv (wk/wv into d_out scratch)
    conv4<<<7168, 256, 0, stream>>>(x, xb, 4096, wq, wqb, 2048,
                                    wk, wkb, 512, wv, wvb);
    // P2: fused qkv gemm + rope (all-bf16, all-async staging)
    qkv_rope_gemm<<<dim3(NQKV / 128, M_ / 128), 256, 0, stream>>>(
        xb, wqb, wkb, wvb, fc, fs, Qr, Kr, Vr);
    // P3: V transpose
    transpose_v<<<dim3(S_ / 64, D_ / 64, B_ * KVH_), 256, 0, stream>>>(Vr, VrT);
    // P4: flash attention
    flash2<<<dim3(S_ / 128, H_, B_), 512, 0, stream>>>(Qr, Kr, VrT, AO);
    // P5: convert wo into freed region0
    conv4<<<2048, 256, 0, stream>>>(wo, wob, 2048, nullptr, nullptr, 0,
                                    nullptr, nullptr, 0, nullptr, nullptr);
    // P6: output projection -> f32 out (overwrites wkb/wvb scratch)
    out_proj_gemm<<<dim3(E_ / 128, M_ / 128), 256, 0, stream>>>(AO, wob, out);
}